// Round 12
// baseline (240.419 us; speedup 1.0000x reference)
//
#include <hip/hip_runtime.h>
#include <stdint.h>

// ---------------- problem constants ----------------
#define B_ROWS 16384
#define NF 26
#define NV 100000
#define ND 13
#define NH 400
#define XPAD 448     // GEMM1 K padded (14 tiles of 32)
#define ZPAD 416     // GEMM2 K padded (13 tiles of 32)
#define EPS 1e-5f

typedef __attribute__((ext_vector_type(8))) short short8;
typedef __attribute__((ext_vector_type(4))) float f32x4;
typedef __attribute__((ext_vector_type(4))) unsigned int uint4v;

__device__ inline float bf2f(unsigned short u) {
    union { unsigned int i; float f; } v; v.i = (unsigned int)u << 16; return v.f;
}
__device__ inline unsigned short f2bf(float f) {
    union { float f; unsigned int i; } v; v.f = f;
    return (unsigned short)((v.i + 0x7fff + ((v.i >> 16) & 1)) >> 16);
}

// ---------------- ws layout (bytes) ----------------
// X  : bf16 [16384][448] (Z2 aliases X after GEMM1)
// Z1 : bf16 [16384][416]
// W1s/W2s staged; base f32[16384]; st = 4 replicas x 1664 f32
#define X_OFF    0
#define Z1_OFF   14680064
#define W1S_OFF  28311552
#define W2S_OFF  28712960
#define BASE_OFF 29085696
#define ST_OFF   29151232

// =====================================================================
// gather (blocks 0..1023) + W-staging/stat-zero (blocks 1024..1212)
// (R5/R11-proven, unchanged)
// =====================================================================
__global__ __launch_bounds__(256) void gather_prep(
    const int* __restrict__ Xcat, const float* __restrict__ Xdense,
    const float* __restrict__ fm1, const float* __restrict__ emb,
    const float* __restrict__ Wd, const float* __restrict__ bd,
    const float* __restrict__ W1, const float* __restrict__ W2,
    unsigned short* __restrict__ X, float* __restrict__ base,
    unsigned short* __restrict__ W1s, unsigned short* __restrict__ W2s,
    float* __restrict__ st)
{
    int tid = threadIdx.x;
    if (blockIdx.x >= 1024) {
        int c = (blockIdx.x - 1024) * 256 + tid;     // 0..48383
        if (c < 256) {
            for (int i = tid; i < 6656; i += 256) st[i] = 0.f;  // 4 replicas
        }
        const float* W; unsigned short* dst; int K; int cc;
        if (c < 25088) { W = W1; dst = W1s; K = 429; cc = c; }
        else           { W = W2; dst = W2s; K = 400; cc = c - 25088; }
        int n  = cc % 448;
        int q  = (cc / 448) & 3;
        int kt = cc / 1792;
        unsigned short o[8];
        #pragma unroll
        for (int j = 0; j < 8; ++j) {
            int k = kt * 32 + q * 8 + j;
            float v = (n < NH && k < K) ? W[(size_t)k * NH + n] : 0.f;
            o[j] = f2bf(v);
        }
        *(uint4v*)(dst + (size_t)cc * 8) = *(uint4v*)o;
        return;
    }
    int r = blockIdx.x * 16 + (tid >> 4);
    int k = tid & 15;
    const int* idxp = Xcat + (size_t)r * NF;
    unsigned short* xrow = X + (size_t)r * XPAD;

    float s = 0.f, ss = 0.f;
    #pragma unroll
    for (int f = 0; f < NF; ++f) {
        int idx = idxp[f];
        float v = emb[((size_t)f * NV + idx) * 16 + k];
        s += v; ss += v * v;
        xrow[f * 16 + k] = f2bf(v);
    }
    float fmsum = fm1[(size_t)k * NV + idxp[k]];
    if (k < NF - 16) fmsum += fm1[(size_t)(k + 16) * NV + idxp[k + 16]];
    float dsum = 0.f;
    if (k < ND) {
        float xd = Xdense[(size_t)r * ND + k];
        dsum = xd * Wd[k];
        xrow[NF * 16 + k] = f2bf(xd);
    }
    xrow[429 + k] = 0;
    if (k < 3) xrow[445 + k] = 0;

    float ix = s * s - ss;
    float rf = fmsum, rd = dsum;
    #pragma unroll
    for (int off = 8; off; off >>= 1) {
        ix += __shfl_xor(ix, off, 16);
        rf += __shfl_xor(rf, off, 16);
        rd += __shfl_xor(rd, off, 16);
    }
    if (k == 0) base[r] = 0.5f * ix + rf + rd + bd[0];
}

// =====================================================================
// gemm_v3: all-register MFMA GEMM — W fragments load directly from the
// staged layout into VGPRs (coalesced 16B/lane, L2-resident), double-
// buffered one tile ahead. No LDS staging, no barriers in the loop,
// no inline asm: compiler's counted vmcnt does the pipelining.
// grid = 512 x 512, __launch_bounds__(512,4) -> 2 blocks/CU, 16 waves/CU.
// Block owns 32 rows; wave (rh,w4): rows rh*16.., col quarter w4.
// =====================================================================
template<int NT, int LDA, bool APPLY_BN>
__global__ __launch_bounds__(512, 4) void gemm_v3(
    const unsigned short* __restrict__ A,
    const unsigned short* __restrict__ Wst,
    const float* __restrict__ bias,
    const float* __restrict__ st_all,   // replica stats for BN input (K2)
    const float* __restrict__ g, const float* __restrict__ be,
    unsigned short* __restrict__ Z, int ldz, int padZ,
    float* __restrict__ st_out, int sumOff, int sqOff)
{
    __shared__ float alpha_s[416], beta_s[416];

    const int tid = threadIdx.x, bid = blockIdx.x;
    const int lane = tid & 63, wv = tid >> 6;
    const int rh = wv >> 2, w4 = wv & 3;
    const int l15 = lane & 15, qh = lane >> 4;
    const int cb = (w4 == 0) ? 0 : (112 + (w4 - 1) * 96);
    const int NFW = (w4 == 0) ? 7 : 6;
    const int arow = bid * 32 + rh * 16 + l15;

    if constexpr (APPLY_BN) {
        if (tid < 416) {
            int c = tid;
            float a = 0.f, b = 0.f;
            if (c < NH) {
                float gs = 0.f, gq = 0.f;
                #pragma unroll
                for (int cp = 0; cp < 4; ++cp) {
                    gs += st_all[cp * 1664 + c];
                    gq += st_all[cp * 1664 + 416 + c];
                }
                float mean = gs * (1.f / 16384.f);
                float var  = gq * (1.f / 16384.f) - mean * mean;
                a = g[c] * rsqrtf(var + EPS);
                b = be[c] - mean * a;
            }
            alpha_s[c] = a; beta_s[c] = b;
        }
        __syncthreads();
    }

    f32x4 acc[7];
    #pragma unroll
    for (int i = 0; i < 7; ++i) acc[i] = f32x4{0.f, 0.f, 0.f, 0.f};

    // W-fragment loader: lane (qh,l15) reads its own B-frag, coalesced.
    auto ldW = [&](int kt, short8* dst) {
        #pragma unroll
        for (int i = 0; i < 7; ++i) if (i < NFW)
            dst[i] = *(const short8*)(
                Wst + ((size_t)((kt * 4 + qh) * 448 + cb + i * 16 + l15)) * 8);
    };

    short8 bfn[7], afn;
    ldW(0, bfn);
    afn = *(const short8*)(A + (size_t)arow * LDA + qh * 8);

    #pragma unroll 1
    for (int kt = 0; kt < NT; ++kt) {
        short8 bf[7];
        #pragma unroll
        for (int i = 0; i < 7; ++i) bf[i] = bfn[i];
        short8 af = afn;
        if (kt + 1 < NT) {
            ldW(kt + 1, bfn);
            afn = *(const short8*)(A + (size_t)arow * LDA + (kt + 1) * 32 + qh * 8);
        }
        if constexpr (APPLY_BN) {
            const int k0 = kt * 32 + qh * 8;
            #pragma unroll
            for (int j = 0; j < 8; ++j) {
                float fa = fmaxf(0.f, alpha_s[k0 + j] * bf2f((unsigned short)af[j]) + beta_s[k0 + j]);
                af[j] = (short)f2bf(fa);
            }
        }
        #pragma unroll
        for (int i = 0; i < 7; ++i) if (i < NFW)
            acc[i] = __builtin_amdgcn_mfma_f32_16x16x32_bf16(af, bf[i], acc[i], 0, 0, 0);
    }

    // ---- epilogue: +bias, bf16 store, per-wave stats -> replica atomics ----
    float* stc = st_out + (bid & 3) * 1664;
    #pragma unroll
    for (int i = 0; i < 7; ++i) if (i < NFW) {
        int col = cb + i * 16 + l15;
        float bv = bias[col];
        float ps = 0.f, pq = 0.f;
        #pragma unroll
        for (int q = 0; q < 4; ++q) {
            float v0 = acc[i][q] + bv;
            Z[(size_t)(bid * 32 + rh * 16 + qh * 4 + q) * ldz + col] = f2bf(v0);
            ps += v0; pq += v0 * v0;
        }
        ps += __shfl_xor(ps, 16, 64); ps += __shfl_xor(ps, 32, 64);
        pq += __shfl_xor(pq, 16, 64); pq += __shfl_xor(pq, 32, 64);
        if (qh == 0) {
            atomicAdd(&stc[sumOff + col], ps);
            atomicAdd(&stc[sqOff + col], pq);
        }
    }
    if (padZ && w4 == 3) {   // zero cols 400..415 for this wave's 16 rows
        #pragma unroll
        for (int q = 0; q < 4; ++q)
            Z[(size_t)(bid * 32 + rh * 16 + qh * 4 + q) * ldz + 400 + l15] = 0;
    }
}

// =====================================================================
// final: BN2 from replicas, then out[r] = base[r] + relu(.)·W3 + b3
// =====================================================================
__global__ __launch_bounds__(256) void final_kernel(
    const unsigned short* __restrict__ Z2,
    const float* __restrict__ st_all,
    const float* __restrict__ g2, const float* __restrict__ be2,
    const float* __restrict__ W3, const float* __restrict__ b3,
    const float* __restrict__ base, float* __restrict__ out)
{
    __shared__ float a2s[NH], b2s[NH], w3s[NH];
    int tid = threadIdx.x;
    for (int c = tid; c < NH; c += 256) {
        float gs = 0.f, gq = 0.f;
        #pragma unroll
        for (int cp = 0; cp < 4; ++cp) {
            gs += st_all[cp * 1664 + 832 + c];
            gq += st_all[cp * 1664 + 1248 + c];
        }
        float mean = gs * (1.f / 16384.f);
        float var  = gq * (1.f / 16384.f) - mean * mean;
        float a = g2[c] * rsqrtf(var + EPS);
        a2s[c] = a;
        b2s[c] = be2[c] - mean * a;
        w3s[c] = W3[c];
    }
    __syncthreads();
    int lane = tid & 63;
    int wv = tid >> 6;
    bool act = lane < 50;
    int cb = lane * 8;
    float al[8], bb[8], w3[8];
    #pragma unroll
    for (int j = 0; j < 8; ++j) {
        al[j] = act ? a2s[cb + j] : 0.f;
        bb[j] = act ? b2s[cb + j] : 0.f;
        w3[j] = act ? w3s[cb + j] : 0.f;
    }
    int r0 = blockIdx.x * 32 + wv * 8;
    float bias3 = b3[0];
    for (int t = 0; t < 8; t += 2) {
        int r = r0 + t;
        float acc0 = 0.f, acc1 = 0.f;
        if (act) {
            short8 z0 = *(const short8*)(Z2 + (size_t)r * ZPAD + cb);
            short8 z1 = *(const short8*)(Z2 + (size_t)(r + 1) * ZPAD + cb);
            #pragma unroll
            for (int j = 0; j < 8; ++j) {
                acc0 += fmaxf(0.f, al[j] * bf2f((unsigned short)z0[j]) + bb[j]) * w3[j];
                acc1 += fmaxf(0.f, al[j] * bf2f((unsigned short)z1[j]) + bb[j]) * w3[j];
            }
        }
        #pragma unroll
        for (int off = 32; off; off >>= 1) {
            acc0 += __shfl_xor(acc0, off, 64);
            acc1 += __shfl_xor(acc1, off, 64);
        }
        if (lane == 0) out[r] = base[r] + acc0 + bias3;
        if (lane == 1) out[r + 1] = base[r + 1] + acc1 + bias3;
    }
}

// =====================================================================
extern "C" void kernel_launch(void* const* d_in, const int* in_sizes, int n_in,
                              void* d_out, int out_size, void* d_ws, size_t ws_size,
                              hipStream_t stream)
{
    const int*   Xcat = (const int*)d_in[0];
    const float* Xd   = (const float*)d_in[1];
    const float* fm1  = (const float*)d_in[2];
    const float* emb  = (const float*)d_in[3];
    const float* Wd   = (const float*)d_in[4];
    const float* bd   = (const float*)d_in[5];
    const float* W1   = (const float*)d_in[6];
    const float* b1   = (const float*)d_in[7];
    const float* g1   = (const float*)d_in[8];
    const float* be1  = (const float*)d_in[9];
    const float* W2   = (const float*)d_in[10];
    const float* b2   = (const float*)d_in[11];
    const float* g2   = (const float*)d_in[12];
    const float* be2  = (const float*)d_in[13];
    const float* W3   = (const float*)d_in[14];
    const float* b3   = (const float*)d_in[15];

    char* ws = (char*)d_ws;
    unsigned short* X   = (unsigned short*)(ws + X_OFF);
    unsigned short* Z1  = (unsigned short*)(ws + Z1_OFF);
    unsigned short* Z2  = X;   // X dead after GEMM1
    unsigned short* W1s = (unsigned short*)(ws + W1S_OFF);
    unsigned short* W2s = (unsigned short*)(ws + W2S_OFF);
    float* base = (float*)(ws + BASE_OFF);
    float* st   = (float*)(ws + ST_OFF);
    float* out  = (float*)d_out;

    // 1: gather + W staging + 4-replica stat zero
    gather_prep<<<1213, 256, 0, stream>>>(Xcat, Xd, fm1, emb, Wd, bd, W1, W2,
                                          X, base, W1s, W2s, st);

    // 2: Z1 = X @ W1 + b1, stats1 (all-register GEMM)
    gemm_v3<14, XPAD, false><<<512, 512, 0, stream>>>(
        X, W1s, b1, nullptr, nullptr, nullptr, Z1, ZPAD, 1, st, 0, 416);

    // 3: Z2 = relu(bn1(Z1)) @ W2 + b2, stats2
    gemm_v3<13, ZPAD, true><<<512, 512, 0, stream>>>(
        Z1, W2s, b2, st, g1, be1, Z2, ZPAD, 0, st, 832, 1248);

    // 4: out = base + relu(bn2(Z2))·W3 + b3
    final_kernel<<<512, 256, 0, stream>>>(Z2, st, g2, be2, W3, b3, base, out);
}

// Round 14
// 89.590 us; speedup vs baseline: 2.6835x; 2.6835x over previous
//
#include <hip/hip_runtime.h>
#include <stdint.h>

// ---------------- problem constants ----------------
#define B_ROWS 16384
#define NF 26
#define NV 100000
#define ND 13
#define NH 400
#define XPAD 448     // GEMM1 K padded (14 tiles of 32)
#define ZPAD 416     // GEMM2 K padded (13 tiles of 32)
#define EPS 1e-5f

typedef __attribute__((ext_vector_type(8))) short short8;
typedef __attribute__((ext_vector_type(4))) float f32x4;
typedef __attribute__((ext_vector_type(4))) unsigned int uint4v;

__device__ inline float bf2f(unsigned short u) {
    union { unsigned int i; float f; } v; v.i = (unsigned int)u << 16; return v.f;
}
__device__ inline unsigned short f2bf(float f) {
    union { float f; unsigned int i; } v; v.f = f;
    return (unsigned short)((v.i + 0x7fff + ((v.i >> 16) & 1)) >> 16);
}

// direct global->LDS DMA, 16B/lane; dest = wave-uniform base + lane*16
// NOTE: one call writes 64 lanes x 16B = 1024B starting at the dest base.
typedef __attribute__((address_space(1))) const unsigned int g_u32;
typedef __attribute__((address_space(3))) unsigned int l_u32;
__device__ __forceinline__ void gload_lds16(const void* g, void* l) {
    __builtin_amdgcn_global_load_lds((g_u32*)g, (l_u32*)l, 16, 0, 0);
}

// ---------------- ws layout (bytes) ----------------
// X  : bf16 [16384][448] (Z2 aliases X after GEMM1)
// Z1 : bf16 [16384][416]
// W1s/W2s staged; base f32[16384]; st = 4 replicas x 1664 f32
#define X_OFF    0
#define Z1_OFF   14680064
#define W1S_OFF  28311552
#define W2S_OFF  28712960
#define BASE_OFF 29085696
#define ST_OFF   29151232

// =====================================================================
// gather (blocks 0..1023) + W-staging/stat-zero (blocks 1024..1212)
// (R5/R11-proven, unchanged)
// =====================================================================
__global__ __launch_bounds__(256) void gather_prep(
    const int* __restrict__ Xcat, const float* __restrict__ Xdense,
    const float* __restrict__ fm1, const float* __restrict__ emb,
    const float* __restrict__ Wd, const float* __restrict__ bd,
    const float* __restrict__ W1, const float* __restrict__ W2,
    unsigned short* __restrict__ X, float* __restrict__ base,
    unsigned short* __restrict__ W1s, unsigned short* __restrict__ W2s,
    float* __restrict__ st)
{
    int tid = threadIdx.x;
    if (blockIdx.x >= 1024) {
        int c = (blockIdx.x - 1024) * 256 + tid;     // 0..48383
        if (c < 256) {
            for (int i = tid; i < 6656; i += 256) st[i] = 0.f;  // 4 replicas
        }
        const float* W; unsigned short* dst; int K; int cc;
        if (c < 25088) { W = W1; dst = W1s; K = 429; cc = c; }
        else           { W = W2; dst = W2s; K = 400; cc = c - 25088; }
        int n  = cc % 448;
        int q  = (cc / 448) & 3;
        int kt = cc / 1792;
        unsigned short o[8];
        #pragma unroll
        for (int j = 0; j < 8; ++j) {
            int k = kt * 32 + q * 8 + j;
            float v = (n < NH && k < K) ? W[(size_t)k * NH + n] : 0.f;
            o[j] = f2bf(v);
        }
        *(uint4v*)(dst + (size_t)cc * 8) = *(uint4v*)o;
        return;
    }
    int r = blockIdx.x * 16 + (tid >> 4);
    int k = tid & 15;
    const int* idxp = Xcat + (size_t)r * NF;
    unsigned short* xrow = X + (size_t)r * XPAD;

    float s = 0.f, ss = 0.f;
    #pragma unroll
    for (int f = 0; f < NF; ++f) {
        int idx = idxp[f];
        float v = emb[((size_t)f * NV + idx) * 16 + k];
        s += v; ss += v * v;
        xrow[f * 16 + k] = f2bf(v);
    }
    float fmsum = fm1[(size_t)k * NV + idxp[k]];
    if (k < NF - 16) fmsum += fm1[(size_t)(k + 16) * NV + idxp[k + 16]];
    float dsum = 0.f;
    if (k < ND) {
        float xd = Xdense[(size_t)r * ND + k];
        dsum = xd * Wd[k];
        xrow[NF * 16 + k] = f2bf(xd);
    }
    xrow[429 + k] = 0;
    if (k < 3) xrow[445 + k] = 0;

    float ix = s * s - ss;
    float rf = fmsum, rd = dsum;
    #pragma unroll
    for (int off = 8; off; off >>= 1) {
        ix += __shfl_xor(ix, off, 16);
        rf += __shfl_xor(rf, off, 16);
        rd += __shfl_xor(rd, off, 16);
    }
    if (k == 0) base[r] = 0.5f * ix + rf + rd + bd[0];
}

// =====================================================================
// gemm_v4: barrier-free per-wave-slice K-loop (R11-proven addressing),
// grid = 512 blocks x 512 threads, 32 rows/block, __launch_bounds__(512,2)
// -> VGPR cap 128 (~95 live), LDS 60,672B -> 2 blocks/CU = 4 waves/SIMD.
// Wave wv = (rh<<2)|w4: rows bid*32+rh*16.., col quarter w4 (NFW=7,6,6,6).
// Slice: 7168B/wave, chunk i at slice + i*512 shorts (1024B = 64x16B DMA).
// =====================================================================
template<int NT, int LDA, bool APPLY_BN>
__global__ __launch_bounds__(512, 2) void gemm_v4(
    const unsigned short* __restrict__ A,
    const unsigned short* __restrict__ Wst,
    const float* __restrict__ bias,
    const float* __restrict__ st_all,   // replica stats for BN input (K2)
    const float* __restrict__ g, const float* __restrict__ be,
    unsigned short* __restrict__ Z, int ldz, int padZ,
    float* __restrict__ st_out, int sumOff, int sqOff)
{
    __shared__ __align__(16) unsigned short slices[28672];  // 8 x 7,168 B
    __shared__ float alpha_s[416], beta_s[416];

    const int tid = threadIdx.x, bid = blockIdx.x;
    const int lane = tid & 63, wv = tid >> 6;
    const int rh = wv >> 2, w4 = wv & 3;
    const int l15 = lane & 15, qh = lane >> 4;
    const int cb = (w4 == 0) ? 0 : (112 + (w4 - 1) * 96);
    const int NFW = (w4 == 0) ? 7 : 6;
    unsigned short* slice = slices + wv * 3584;   // 3584 shorts = 7168 B
    const int arow = bid * 32 + rh * 16 + l15;

    if constexpr (APPLY_BN) {
        if (tid < 416) {
            int c = tid;
            float a = 0.f, b = 0.f;
            if (c < NH) {
                float gs = 0.f, gq = 0.f;
                #pragma unroll
                for (int cp = 0; cp < 4; ++cp) {
                    gs += st_all[cp * 1664 + c];
                    gq += st_all[cp * 1664 + 416 + c];
                }
                float mean = gs * (1.f / 16384.f);
                float var  = gq * (1.f / 16384.f) - mean * mean;
                a = g[c] * rsqrtf(var + EPS);
                b = be[c] - mean * a;
            }
            alpha_s[c] = a; beta_s[c] = b;
        }
        __syncthreads();
    }

    f32x4 acc[7];
    #pragma unroll
    for (int i = 0; i < 7; ++i) acc[i] = f32x4{0.f, 0.f, 0.f, 0.f};

    auto stageW = [&](int kt) {
        #pragma unroll
        for (int i = 0; i < 7; ++i) if (i < NFW) {
            int ci = (kt * 4 + qh) * 448 + cb + i * 16 + l15;
            gload_lds16(Wst + (size_t)ci * 8, slice + i * 512);   // 1024B chunk
        }
    };

    stageW(0);
    short8 af_n = *(const short8*)(A + (size_t)arow * LDA + qh * 8);

    for (int kt = 0; kt < NT; ++kt) {
        asm volatile("s_waitcnt vmcnt(0)" ::: "memory");   // slice + af ready
        __builtin_amdgcn_sched_barrier(0);
        short8 bf[7];
        #pragma unroll
        for (int i = 0; i < 7; ++i) if (i < NFW)
            bf[i] = *(const short8*)(slice + i * 512 + lane * 8);
        short8 af = af_n;
        asm volatile("s_waitcnt lgkmcnt(0)" ::: "memory"); // ds_reads done
        __builtin_amdgcn_sched_barrier(0);
        if (kt + 1 < NT) {
            stageW(kt + 1);                                 // overwrite slice
            af_n = *(const short8*)(A + (size_t)arow * LDA + (kt + 1) * 32 + qh * 8);
        }
        if constexpr (APPLY_BN) {
            const int k0 = kt * 32 + qh * 8;
            #pragma unroll
            for (int j = 0; j < 8; ++j) {
                float fa = fmaxf(0.f, alpha_s[k0 + j] * bf2f((unsigned short)af[j]) + beta_s[k0 + j]);
                af[j] = (short)f2bf(fa);
            }
        }
        #pragma unroll
        for (int i = 0; i < 7; ++i) if (i < NFW)
            acc[i] = __builtin_amdgcn_mfma_f32_16x16x32_bf16(af, bf[i], acc[i], 0, 0, 0);
    }

    // ---- epilogue: +bias, bf16 store, per-wave stats -> replica atomics ----
    float* stc = st_out + (bid & 3) * 1664;
    #pragma unroll
    for (int i = 0; i < 7; ++i) if (i < NFW) {
        int col = cb + i * 16 + l15;
        float bv = bias[col];
        float ps = 0.f, pq = 0.f;
        #pragma unroll
        for (int q = 0; q < 4; ++q) {
            float v0 = acc[i][q] + bv;
            Z[(size_t)(bid * 32 + rh * 16 + qh * 4 + q) * ldz + col] = f2bf(v0);
            ps += v0; pq += v0 * v0;
        }
        ps += __shfl_xor(ps, 16, 64); ps += __shfl_xor(ps, 32, 64);
        pq += __shfl_xor(pq, 16, 64); pq += __shfl_xor(pq, 32, 64);
        if (qh == 0) {
            atomicAdd(&stc[sumOff + col], ps);
            atomicAdd(&stc[sqOff + col], pq);
        }
    }
    if (padZ && w4 == 3) {   // zero cols 400..415 for this wave's 16 rows
        #pragma unroll
        for (int q = 0; q < 4; ++q)
            Z[(size_t)(bid * 32 + rh * 16 + qh * 4 + q) * ldz + 400 + l15] = 0;
    }
}

// =====================================================================
// final: BN2 from replicas, then out[r] = base[r] + relu(.)·W3 + b3
// =====================================================================
__global__ __launch_bounds__(256) void final_kernel(
    const unsigned short* __restrict__ Z2,
    const float* __restrict__ st_all,
    const float* __restrict__ g2, const float* __restrict__ be2,
    const float* __restrict__ W3, const float* __restrict__ b3,
    const float* __restrict__ base, float* __restrict__ out)
{
    __shared__ float a2s[NH], b2s[NH], w3s[NH];
    int tid = threadIdx.x;
    for (int c = tid; c < NH; c += 256) {
        float gs = 0.f, gq = 0.f;
        #pragma unroll
        for (int cp = 0; cp < 4; ++cp) {
            gs += st_all[cp * 1664 + 832 + c];
            gq += st_all[cp * 1664 + 1248 + c];
        }
        float mean = gs * (1.f / 16384.f);
        float var  = gq * (1.f / 16384.f) - mean * mean;
        float a = g2[c] * rsqrtf(var + EPS);
        a2s[c] = a;
        b2s[c] = be2[c] - mean * a;
        w3s[c] = W3[c];
    }
    __syncthreads();
    int lane = tid & 63;
    int wv = tid >> 6;
    bool act = lane < 50;
    int cb = lane * 8;
    float al[8], bb[8], w3[8];
    #pragma unroll
    for (int j = 0; j < 8; ++j) {
        al[j] = act ? a2s[cb + j] : 0.f;
        bb[j] = act ? b2s[cb + j] : 0.f;
        w3[j] = act ? w3s[cb + j] : 0.f;
    }
    int r0 = blockIdx.x * 32 + wv * 8;
    float bias3 = b3[0];
    for (int t = 0; t < 8; t += 2) {
        int r = r0 + t;
        float acc0 = 0.f, acc1 = 0.f;
        if (act) {
            short8 z0 = *(const short8*)(Z2 + (size_t)r * ZPAD + cb);
            short8 z1 = *(const short8*)(Z2 + (size_t)(r + 1) * ZPAD + cb);
            #pragma unroll
            for (int j = 0; j < 8; ++j) {
                acc0 += fmaxf(0.f, al[j] * bf2f((unsigned short)z0[j]) + bb[j]) * w3[j];
                acc1 += fmaxf(0.f, al[j] * bf2f((unsigned short)z1[j]) + bb[j]) * w3[j];
            }
        }
        #pragma unroll
        for (int off = 32; off; off >>= 1) {
            acc0 += __shfl_xor(acc0, off, 64);
            acc1 += __shfl_xor(acc1, off, 64);
        }
        if (lane == 0) out[r] = base[r] + acc0 + bias3;
        if (lane == 1) out[r + 1] = base[r + 1] + acc1 + bias3;
    }
}

// =====================================================================
extern "C" void kernel_launch(void* const* d_in, const int* in_sizes, int n_in,
                              void* d_out, int out_size, void* d_ws, size_t ws_size,
                              hipStream_t stream)
{
    const int*   Xcat = (const int*)d_in[0];
    const float* Xd   = (const float*)d_in[1];
    const float* fm1  = (const float*)d_in[2];
    const float* emb  = (const float*)d_in[3];
    const float* Wd   = (const float*)d_in[4];
    const float* bd   = (const float*)d_in[5];
    const float* W1   = (const float*)d_in[6];
    const float* b1   = (const float*)d_in[7];
    const float* g1   = (const float*)d_in[8];
    const float* be1  = (const float*)d_in[9];
    const float* W2   = (const float*)d_in[10];
    const float* b2   = (const float*)d_in[11];
    const float* g2   = (const float*)d_in[12];
    const float* be2  = (const float*)d_in[13];
    const float* W3   = (const float*)d_in[14];
    const float* b3   = (const float*)d_in[15];

    char* ws = (char*)d_ws;
    unsigned short* X   = (unsigned short*)(ws + X_OFF);
    unsigned short* Z1  = (unsigned short*)(ws + Z1_OFF);
    unsigned short* Z2  = X;   // X dead after GEMM1
    unsigned short* W1s = (unsigned short*)(ws + W1S_OFF);
    unsigned short* W2s = (unsigned short*)(ws + W2S_OFF);
    float* base = (float*)(ws + BASE_OFF);
    float* st   = (float*)(ws + ST_OFF);
    float* out  = (float*)d_out;

    // 1: gather + W staging + 4-replica stat zero
    gather_prep<<<1213, 256, 0, stream>>>(Xcat, Xd, fm1, emb, Wd, bd, W1, W2,
                                          X, base, W1s, W2s, st);

    // 2: Z1 = X @ W1 + b1, stats1
    gemm_v4<14, XPAD, false><<<512, 512, 0, stream>>>(
        X, W1s, b1, nullptr, nullptr, nullptr, Z1, ZPAD, 1, st, 0, 416);

    // 3: Z2 = relu(bn1(Z1)) @ W2 + b2, stats2
    gemm_v4<13, ZPAD, true><<<512, 512, 0, stream>>>(
        Z1, W2s, b2, st, g1, be1, Z2, ZPAD, 0, st, 832, 1248);

    // 4: out = base + relu(bn2(Z2))·W3 + b3
    final_kernel<<<512, 256, 0, stream>>>(Z2, st, g2, be2, W3, b3, base, out);
}